// Round 5
// baseline (1075.979 us; speedup 1.0000x reference)
//
#include <hip/hip_runtime.h>
#include <math.h>

#define DM   2048
#define DFF  8192
#define NH   16
#define HD   128
#define SEQ  2048
#define MROWS 4096   // BATCH * SEQ

typedef __attribute__((ext_vector_type(4))) float  f32x4;
typedef __attribute__((ext_vector_type(8))) __bf16 bf16x8;
typedef __attribute__((ext_vector_type(4))) short  short4_t;

#define VMCNT(n) asm volatile("s_waitcnt vmcnt(" #n ")" ::: "memory")
#define LGKM0()  asm volatile("s_waitcnt lgkmcnt(0)" ::: "memory")

__device__ inline unsigned short f2bf(float f) {
  union { float f; unsigned int u; } x; x.f = f;
  unsigned int r = x.u + 0x7FFFu + ((x.u >> 16) & 1u);
  return (unsigned short)(r >> 16);
}

__device__ inline void gload16(const void* g, void* l) {
  __builtin_amdgcn_global_load_lds(
      (const __attribute__((address_space(1))) unsigned int*)g,
      (__attribute__((address_space(3))) unsigned int*)l, 16, 0, 0);
}

// ---------------- LayerNorm (f32 in, bf16 out) ----------------
__global__ __launch_bounds__(256) void ln_kernel(
    const float* __restrict__ in, const float* __restrict__ gw,
    const float* __restrict__ bw, unsigned short* __restrict__ out)
{
  const int row = blockIdx.x;
  const float* xr = in + (size_t)row * DM;
  const int t = threadIdx.x, lane = t & 63, w = t >> 6;
  float4 v0 = ((const float4*)xr)[t];
  float4 v1 = ((const float4*)xr)[t + 256];
  float s = v0.x+v0.y+v0.z+v0.w + v1.x+v1.y+v1.z+v1.w;
  float s2 = v0.x*v0.x+v0.y*v0.y+v0.z*v0.z+v0.w*v0.w
           + v1.x*v1.x+v1.y*v1.y+v1.z*v1.z+v1.w*v1.w;
  #pragma unroll
  for (int off = 32; off; off >>= 1) { s += __shfl_xor(s, off); s2 += __shfl_xor(s2, off); }
  __shared__ float rs[4], rs2[4];
  if (lane == 0) { rs[w] = s; rs2[w] = s2; }
  __syncthreads();
  s = rs[0] + rs[1] + rs[2] + rs[3];
  s2 = rs2[0] + rs2[1] + rs2[2] + rs2[3];
  const float mu = s * (1.0f / DM);
  const float var = s2 * (1.0f / DM) - mu * mu;
  const float rstd = rsqrtf(var + 1e-5f);
  float4 g0 = ((const float4*)gw)[t],     b0 = ((const float4*)bw)[t];
  float4 g1 = ((const float4*)gw)[t+256], b1 = ((const float4*)bw)[t+256];
  unsigned short* o = out + (size_t)row * DM;
  int i0 = t * 4, i1 = (t + 256) * 4;
  o[i0+0] = f2bf((v0.x-mu)*rstd*g0.x + b0.x);
  o[i0+1] = f2bf((v0.y-mu)*rstd*g0.y + b0.y);
  o[i0+2] = f2bf((v0.z-mu)*rstd*g0.z + b0.z);
  o[i0+3] = f2bf((v0.w-mu)*rstd*g0.w + b0.w);
  o[i1+0] = f2bf((v1.x-mu)*rstd*g1.x + b1.x);
  o[i1+1] = f2bf((v1.y-mu)*rstd*g1.y + b1.y);
  o[i1+2] = f2bf((v1.z-mu)*rstd*g1.z + b1.z);
  o[i1+3] = f2bf((v1.w-mu)*rstd*g1.w + b1.w);
}

// ------- weight transpose + f32->bf16: in[nrows][ncols] -> out[ncols][nrows] -------
__global__ void transpose_kernel(const float* __restrict__ in,
                                 unsigned short* __restrict__ out,
                                 int nrows, int ncols)
{
  __shared__ float tile[32][33];
  const int bx = blockIdx.x * 32;  // col base
  const int by = blockIdx.y * 32;  // row base
  const int tx = threadIdx.x, ty = threadIdx.y;
  #pragma unroll
  for (int i = ty; i < 32; i += 8)
    tile[i][tx] = in[(size_t)(by + i) * ncols + bx + tx];
  __syncthreads();
  #pragma unroll
  for (int i = ty; i < 32; i += 8)
    out[(size_t)(bx + i) * nrows + by + tx] = f2bf(tile[tx][i]);
}

// ---------------- GEMM 256x256, BK=32, 8 waves, ring-4 LDS, counted vmcnt ----------------
// C = A[M][K](bf16) @ Bt[N][K](bf16)^T, fused epilogues.
// Ring discipline per K-tile T: { vmcnt(counted); s_barrier; stage(T+3); ds_read(T&3);
// MFMA(setprio); lgkmcnt(0) } -- one barrier/tile, loads stay in flight across it (T4).
// LDS chunk swizzle cc ^= row&3 on BOTH stage-source and read (T2, involution).
enum { EP_Q = 0, EP_K = 1, EP_V = 2, EP_WO = 3, EP_FFN1 = 4, EP_FFN2 = 5 };

template <int MODE>
__global__ __launch_bounds__(512, 2) void gemm_kernel(
    const unsigned short* __restrict__ A,
    const unsigned short* __restrict__ Bt,
    int K, int N,
    const float* __restrict__ res,
    const float* __restrict__ bias,
    void* __restrict__ out)
{
  __shared__ unsigned short As[4][8192];   // 4 x 256 rows x 32 cols (16KB each)
  __shared__ unsigned short Bs[4][8192];

  const int t = threadIdx.x;
  const int w = t >> 6, lane = t & 63;
  const int wm = w >> 2, wn = w & 3;        // wave grid 2(M) x 4(N)
  const int c = lane & 15, g = lane >> 4;

  // XCD-aware bijective block swizzle (nwg % 8 == 0 for all our launches)
  const int gx = gridDim.x, nwg = gx * gridDim.y;
  int bid = blockIdx.y * gx + blockIdx.x;
  if ((nwg & 7) == 0) bid = (bid & 7) * (nwg >> 3) + (bid >> 3);
  const long bm = (long)(bid % gx) * 256;
  const long bn = (long)(bid / gx) * 256;

  const int NT = K >> 5;

  // staging: one K-tile = A(256x32) + B(256x32); 2+2 gload16 per thread
  const int srow = t >> 2;                  // 0..127
  const int scc  = t & 3;
  auto stage = [&](int kt, int slot) {
    #pragma unroll
    for (int l = 0; l < 2; l++) {
      const int row = l * 128 + srow;
      const int cca = scc ^ (row & 3);      // inverse (== forward) swizzle
      gload16(A  + (bm + row) * (size_t)K + kt * 32 + cca * 8,
              &As[slot][l * 4096 + w * 512]);
      gload16(Bt + (bn + row) * (size_t)K + kt * 32 + cca * 8,
              &Bs[slot][l * 4096 + w * 512]);
    }
  };

  f32x4 acc[8][4];
  #pragma unroll
  for (int m = 0; m < 8; m++)
    #pragma unroll
    for (int n = 0; n < 4; n++) acc[m][n] = (f32x4){0.f, 0.f, 0.f, 0.f};

  // prologue: stage tiles 0,1,2 (12 loads in flight)
  stage(0, 0); stage(1, 1); stage(2, 2);

  const int sw = (g ^ (c & 3)) * 8;         // swizzled chunk offset (shorts)

  for (int T = 0; T < NT; T++) {
    if (T < NT - 2)      { VMCNT(8); }      // tile T landed (T+1,T+2 may fly)
    else if (T == NT - 2){ VMCNT(4); }
    else                 { VMCNT(0); }
    __builtin_amdgcn_s_barrier();
    if (T + 3 < NT) stage(T + 3, (T + 3) & 3);

    const unsigned short* LA = As[T & 3];
    const unsigned short* LB = Bs[T & 3];
    bf16x8 a4[8], b4[4];
    #pragma unroll
    for (int n = 0; n < 4; n++)
      b4[n] = *(const bf16x8*)&LB[(wn * 64 + n * 16 + c) * 32 + sw];
    #pragma unroll
    for (int m = 0; m < 8; m++)
      a4[m] = *(const bf16x8*)&LA[(wm * 128 + m * 16 + c) * 32 + sw];

    __builtin_amdgcn_s_setprio(1);
    #pragma unroll
    for (int m = 0; m < 8; m++)
      #pragma unroll
      for (int n = 0; n < 4; n++)
        acc[m][n] = __builtin_amdgcn_mfma_f32_16x16x32_bf16(a4[m], b4[n], acc[m][n], 0, 0, 0);
    __builtin_amdgcn_s_setprio(0);
    LGKM0();   // all ds_reads of this slot complete before next barrier
  }

  // ---------------- epilogue ----------------
  #pragma unroll
  for (int m = 0; m < 8; m++) {
    const long row0 = bm + wm * 128 + m * 16 + g * 4;
    #pragma unroll
    for (int n = 0; n < 4; n++) {
      const long col = bn + wn * 64 + n * 16 + c;
      #pragma unroll
      for (int r = 0; r < 4; r++) {
        const long row = row0 + r;
        float v = acc[m][n][r];
        if constexpr (MODE == EP_Q) {
          ((unsigned short*)out)[(((row >> 11) * NH + (col >> 7)) * (long)SEQ + (row & 2047)) * HD + (col & 127)] =
              f2bf(v * 0.08838834764831845f);
        } else if constexpr (MODE == EP_K) {
          ((unsigned short*)out)[(((row >> 11) * NH + (col >> 7)) * (long)SEQ + (row & 2047)) * HD + (col & 127)] = f2bf(v);
        } else if constexpr (MODE == EP_V) {
          ((unsigned short*)out)[(((row >> 11) * NH + (col >> 7)) * (long)HD + (col & 127)) * SEQ + (row & 2047)] = f2bf(v);
        } else if constexpr (MODE == EP_WO) {
          ((float*)out)[row * DM + col] = res[row * DM + col] + v;
        } else if constexpr (MODE == EP_FFN1) {
          // tanh-approx GELU (|err| < 3e-3, VALU-cheap vs erff)
          float u = v + bias[col];
          float y = 0.7978845608028654f * (u + 0.044715f * u * u * u);
          float e = __expf(-2.0f * fabsf(y));
          float th = (1.0f - e) / (1.0f + e);
          th = (y < 0.0f) ? -th : th;
          ((unsigned short*)out)[row * (long)N + col] = f2bf(0.5f * u * (1.0f + th));
        } else { // EP_FFN2
          ((float*)out)[row * DM + col] = res[row * DM + col] + v + bias[col];
        }
      }
    }
  }
}

// ---------------- Flash attention, causal + alibi, LDS-staged K/V ----------------
__global__ __launch_bounds__(256) void attn_kernel(
    const unsigned short* __restrict__ Q,
    const unsigned short* __restrict__ Kg,
    const unsigned short* __restrict__ Vt,
    const float* __restrict__ alibi,
    unsigned short* __restrict__ Out)
{
  __shared__ unsigned short lds[2][16384];   // 2 x (16KB K | 16KB V)

  const int bh = blockIdx.x;
  const int h = bh & (NH - 1);
  const int b = bh >> 4;
  const int j = blockIdx.y;                  // pair 0..15
  const int t = threadIdx.x;
  const int w = t >> 6;                      // wave 0..3
  const int lane = t & 63;
  const int c = lane & 15, g = lane >> 4;
  const int cx = (c & 7) << 4;               // read-side XOR swizzle

  const char* KpB = (const char*)(Kg + (size_t)bh * SEQ * HD);
  const char* VpB = (const char*)(Vt + (size_t)bh * SEQ * HD);
  const unsigned short* Qp = Q + (size_t)bh * SEQ * HD;
  const float* Ah = alibi + (size_t)h * SEQ * SEQ;

  #pragma unroll 1
  for (int half = 0; half < 2; half++) {
    const int cidx = half ? (31 - j) : j;
    const int nt = cidx + 1;                 // kv tiles for this chunk
    const int qb = cidx * 64;
    const int q0 = qb + w * 16, qc = q0 + c;

    bf16x8 qf[4];
    #pragma unroll
    for (int dt = 0; dt < 4; dt++)
      qf[dt] = *(const bf16x8*)(Qp + (size_t)qc * HD + dt * 32 + g * 8);

    f32x4 oacc[8];
    #pragma unroll
    for (int d = 0; d < 8; d++) oacc[d] = (f32x4){0.f, 0.f, 0.f, 0.f};
    float m_run = -1e30f, s_run = 0.f;
    const float* Ap = Ah + (size_t)qc * SEQ;

    auto stage = [&](int tt, unsigned short* dst) {
      const size_t kvo = (size_t)tt * 64;
      #pragma unroll
      for (int k = 0; k < 8; k++) {
        const int o = w * 8192 + k * 1024 + lane * 16;
        if (w < 2) {
          const int so = o ^ (((o >> 8) & 7) << 4);        // inverse swizzle (involution)
          gload16(KpB + kvo * 256 + so, dst + ((w * 8192 + k * 1024) >> 1));
        } else {
          const int o2 = o - 16384;
          const int d = o2 >> 7, win = o2 & 127;
          gload16(VpB + (size_t)d * 4096 + kvo * 2 + (win ^ ((d & 7) << 4)),
                  dst + ((w * 8192 + k * 1024) >> 1));
        }
      }
    };

    stage(0, lds[0]);
    __syncthreads();
    int buf = 0;

    for (int tt = 0; tt < nt; tt++) {
      if (tt + 1 < nt) stage(tt + 1, lds[buf ^ 1]);
      const unsigned short* LK = lds[buf];
      const unsigned short* LV = lds[buf] + 8192;
      const int kv0 = tt * 64;

      f32x4 sc[4];
      #pragma unroll
      for (int st = 0; st < 4; st++) sc[st] = (f32x4){0.f, 0.f, 0.f, 0.f};
      #pragma unroll
      for (int dt = 0; dt < 4; dt++)
        #pragma unroll
        for (int st = 0; st < 4; st++) {
          bf16x8 kf = *(const bf16x8*)&LK[(st * 4096 + c * 256 + ((dt * 64 + g * 16) ^ cx)) >> 1];
          sc[st] = __builtin_amdgcn_mfma_f32_16x16x32_bf16(kf, qf[dt], sc[st], 0, 0, 0);
        }

      float4 al[4];
      #pragma unroll
      for (int st = 0; st < 4; st++) al[st] = *(const float4*)(Ap + kv0 + st * 16 + g * 4);
      float scr[16];
      #pragma unroll
      for (int st = 0; st < 4; st++) {
        scr[st*4+0] = (kv0 + st*16 + g*4 + 0 > qc) ? -1e30f : sc[st][0] + al[st].x;
        scr[st*4+1] = (kv0 + st*16 + g*4 + 1 > qc) ? -1e30f : sc[st][1] + al[st].y;
        scr[st*4+2] = (kv0 + st*16 + g*4 + 2 > qc) ? -1e30f : sc[st][2] + al[st].z;
        scr[st*4+3] = (kv0 + st*16 + g*4 + 3 > qc) ? -1e30f : sc[st][3] + al[st].w;
      }

      float tm = scr[0];
      #pragma unroll
      for (int i = 1; i < 16; i++) tm = fmaxf(tm, scr[i]);
      tm = fmaxf(tm, __shfl_xor(tm, 16));
      tm = fmaxf(tm, __shfl_xor(tm, 32));
      const float m_new = fmaxf(m_run, tm);
      const float corr = __expf(m_run - m_new);
      float pv[16]; float ps = 0.f;
      #pragma unroll
      for (int i = 0; i < 16; i++) { pv[i] = __expf(scr[i] - m_new); ps += pv[i]; }
      ps += __shfl_xor(ps, 16);
      ps += __shfl_xor(ps, 32);
      s_run = s_run * corr + ps;
      m_run = m_new;

      short4_t pf[4];
      #pragma unroll
      for (int st = 0; st < 4; st++) {
        pf[st][0] = (short)f2bf(pv[st*4+0]); pf[st][1] = (short)f2bf(pv[st*4+1]);
        pf[st][2] = (short)f2bf(pv[st*4+2]); pf[st][3] = (short)f2bf(pv[st*4+3]);
      }

      float cf[4];
      #pragma unroll
      for (int r = 0; r < 4; r++) cf[r] = __shfl(corr, g * 4 + r);

      #pragma unroll
      for (int dt = 0; dt < 8; dt++) {
        f32x4 o = oacc[dt];
        o[0] *= cf[0]; o[1] *= cf[1]; o[2] *= cf[2]; o[3] *= cf[3];
        #pragma unroll
        for (int st = 0; st < 4; st++) {
          short4_t vf = *(const short4_t*)&LV[((dt * 16 + c) * 128 + ((st * 32 + g * 8) ^ cx)) >> 1];
          o = __builtin_amdgcn_mfma_f32_16x16x16bf16_1k(pf[st], vf, o, 0, 0, 0);
        }
        oacc[dt] = o;
      }

      __syncthreads();
      buf ^= 1;
    }

    float inv[4];
    #pragma unroll
    for (int r = 0; r < 4; r++) inv[r] = 1.0f / __shfl(s_run, g * 4 + r);
    #pragma unroll
    for (int dt = 0; dt < 8; dt++)
      #pragma unroll
      for (int r = 0; r < 4; r++)
        Out[(size_t)(b * SEQ + q0 + g * 4 + r) * DM + h * HD + dt * 16 + c] =
            f2bf(oacc[dt][r] * inv[r]);
  }
}

// ---------------- launch ----------------
extern "C" void kernel_launch(void* const* d_in, const int* in_sizes, int n_in,
                              void* d_out, int out_size, void* d_ws, size_t ws_size,
                              hipStream_t stream) {
  const float* x     = (const float*)d_in[0];
  const float* alibi = (const float*)d_in[1];
  const float* Wq    = (const float*)d_in[2];
  const float* Wk    = (const float*)d_in[3];
  const float* Wv    = (const float*)d_in[4];
  const float* Wo    = (const float*)d_in[5];
  const float* ln1g  = (const float*)d_in[6];
  const float* ln1b  = (const float*)d_in[7];
  const float* ln2g  = (const float*)d_in[8];
  const float* ln2b  = (const float*)d_in[9];
  const float* w1    = (const float*)d_in[10];
  const float* b1    = (const float*)d_in[11];
  const float* w2    = (const float*)d_in[12];
  const float* b2    = (const float*)d_in[13];

  char* ws = (char*)d_ws;
  float*          hbuf = (float*)(ws);                                // 32MB f32 h
  unsigned short* xn   = (unsigned short*)(ws + (32ull  << 20));      // 16MB bf16 (xn, later n2)
  unsigned short* qb   = (unsigned short*)(ws + (48ull  << 20));      // 16MB
  unsigned short* kb   = (unsigned short*)(ws + (64ull  << 20));      // 16MB
  unsigned short* vt   = (unsigned short*)(ws + (80ull  << 20));      // 16MB
  unsigned short* ao   = (unsigned short*)(ws + (96ull  << 20));      // 16MB attn_out
  unsigned short* wt   = (unsigned short*)(ws + (112ull << 20));      // 32MB weight scratch
  unsigned short* a1   = (unsigned short*)(ws + (48ull  << 20));      // 64MB (reuses q/k/vt/ao)

  dim3 blk256(256);
  dim3 blk512(512);
  dim3 tb(32, 8);

  ln_kernel<<<MROWS, blk256, 0, stream>>>(x, ln1g, ln1b, xn);

  transpose_kernel<<<dim3(DM/32, DM/32), tb, 0, stream>>>(Wq, wt, DM, DM);
  gemm_kernel<EP_Q><<<dim3(MROWS/256, DM/256), blk512, 0, stream>>>(xn, wt, DM, DM, nullptr, nullptr, qb);
  transpose_kernel<<<dim3(DM/32, DM/32), tb, 0, stream>>>(Wk, wt, DM, DM);
  gemm_kernel<EP_K><<<dim3(MROWS/256, DM/256), blk512, 0, stream>>>(xn, wt, DM, DM, nullptr, nullptr, kb);
  transpose_kernel<<<dim3(DM/32, DM/32), tb, 0, stream>>>(Wv, wt, DM, DM);
  gemm_kernel<EP_V><<<dim3(MROWS/256, DM/256), blk512, 0, stream>>>(xn, wt, DM, DM, nullptr, nullptr, vt);

  attn_kernel<<<dim3(NH * 2, 16), blk256, 0, stream>>>(qb, kb, vt, alibi, ao);

  transpose_kernel<<<dim3(DM/32, DM/32), tb, 0, stream>>>(Wo, wt, DM, DM);
  gemm_kernel<EP_WO><<<dim3(MROWS/256, DM/256), blk512, 0, stream>>>(ao, wt, DM, DM, x, nullptr, hbuf);

  ln_kernel<<<MROWS, blk256, 0, stream>>>(hbuf, ln2g, ln2b, xn);

  transpose_kernel<<<dim3(DFF/32, DM/32), tb, 0, stream>>>(w1, wt, DM, DFF);
  gemm_kernel<EP_FFN1><<<dim3(MROWS/256, DFF/256), blk512, 0, stream>>>(xn, wt, DM, DFF, nullptr, b1, a1);

  transpose_kernel<<<dim3(DM/32, DFF/32), tb, 0, stream>>>(w2, wt, DFF, DM);
  gemm_kernel<EP_FFN2><<<dim3(MROWS/256, DM/256), blk512, 0, stream>>>(a1, wt, DFF, DM, hbuf, b2, (float*)d_out);
}

// Round 6
// 686.563 us; speedup vs baseline: 1.5672x; 1.5672x over previous
//
#include <hip/hip_runtime.h>
#include <math.h>

#define DM   2048
#define DFF  8192
#define NH   16
#define HD   128
#define SEQ  2048
#define MROWS 4096   // BATCH * SEQ

typedef __attribute__((ext_vector_type(4))) float  f32x4;
typedef __attribute__((ext_vector_type(8))) __bf16 bf16x8;
typedef __attribute__((ext_vector_type(4))) short  short4_t;

#define VMCNT(n) asm volatile("s_waitcnt vmcnt(" #n ")" ::: "memory")
#define LGKM0()  asm volatile("s_waitcnt lgkmcnt(0)" ::: "memory")
#define SBAR()   asm volatile("s_barrier" ::: "memory")
#define SCHEDB() __builtin_amdgcn_sched_barrier(0)

__device__ inline unsigned short f2bf(float f) {
  union { float f; unsigned int u; } x; x.f = f;
  unsigned int r = x.u + 0x7FFFu + ((x.u >> 16) & 1u);
  return (unsigned short)(r >> 16);
}

__device__ inline void gload16(const void* g, void* l) {
  __builtin_amdgcn_global_load_lds(
      (const __attribute__((address_space(1))) unsigned int*)g,
      (__attribute__((address_space(3))) unsigned int*)l, 16, 0, 0);
}

// ---------------- LayerNorm (f32 in, bf16 out) ----------------
__global__ __launch_bounds__(256) void ln_kernel(
    const float* __restrict__ in, const float* __restrict__ gw,
    const float* __restrict__ bw, unsigned short* __restrict__ out)
{
  const int row = blockIdx.x;
  const float* xr = in + (size_t)row * DM;
  const int t = threadIdx.x, lane = t & 63, w = t >> 6;
  float4 v0 = ((const float4*)xr)[t];
  float4 v1 = ((const float4*)xr)[t + 256];
  float s = v0.x+v0.y+v0.z+v0.w + v1.x+v1.y+v1.z+v1.w;
  float s2 = v0.x*v0.x+v0.y*v0.y+v0.z*v0.z+v0.w*v0.w
           + v1.x*v1.x+v1.y*v1.y+v1.z*v1.z+v1.w*v1.w;
  #pragma unroll
  for (int off = 32; off; off >>= 1) { s += __shfl_xor(s, off); s2 += __shfl_xor(s2, off); }
  __shared__ float rs[4], rs2[4];
  if (lane == 0) { rs[w] = s; rs2[w] = s2; }
  __syncthreads();
  s = rs[0] + rs[1] + rs[2] + rs[3];
  s2 = rs2[0] + rs2[1] + rs2[2] + rs2[3];
  const float mu = s * (1.0f / DM);
  const float var = s2 * (1.0f / DM) - mu * mu;
  const float rstd = rsqrtf(var + 1e-5f);
  float4 g0 = ((const float4*)gw)[t],     b0 = ((const float4*)bw)[t];
  float4 g1 = ((const float4*)gw)[t+256], b1 = ((const float4*)bw)[t+256];
  unsigned short* o = out + (size_t)row * DM;
  int i0 = t * 4, i1 = (t + 256) * 4;
  o[i0+0] = f2bf((v0.x-mu)*rstd*g0.x + b0.x);
  o[i0+1] = f2bf((v0.y-mu)*rstd*g0.y + b0.y);
  o[i0+2] = f2bf((v0.z-mu)*rstd*g0.z + b0.z);
  o[i0+3] = f2bf((v0.w-mu)*rstd*g0.w + b0.w);
  o[i1+0] = f2bf((v1.x-mu)*rstd*g1.x + b1.x);
  o[i1+1] = f2bf((v1.y-mu)*rstd*g1.y + b1.y);
  o[i1+2] = f2bf((v1.z-mu)*rstd*g1.z + b1.z);
  o[i1+3] = f2bf((v1.w-mu)*rstd*g1.w + b1.w);
}

// ------- weight transpose + f32->bf16: in[nrows][ncols] -> out[ncols][nrows] -------
__global__ void transpose_kernel(const float* __restrict__ in,
                                 unsigned short* __restrict__ out,
                                 int nrows, int ncols)
{
  __shared__ float tile[32][33];
  const int bx = blockIdx.x * 32;  // col base
  const int by = blockIdx.y * 32;  // row base
  const int tx = threadIdx.x, ty = threadIdx.y;
  #pragma unroll
  for (int i = ty; i < 32; i += 8)
    tile[i][tx] = in[(size_t)(by + i) * ncols + bx + tx];
  __syncthreads();
  #pragma unroll
  for (int i = ty; i < 32; i += 8)
    out[(size_t)(bx + i) * nrows + by + tx] = f2bf(tile[tx][i]);
}

// ---- GEMM: 8-phase schedule. BM=128, BN=256, BK=64, 8 waves (2M x 4N). ----
// C = A[M][K](bf16) @ Bt[N][K](bf16)^T, fused epilogues.
// LDS: 2 slots x {A[128][64], B0[128][64], B1[128][64]} = 96KB, chunk-swizzled
// (chunk16 ^= row&7, both sides -> involution). 4 phases/K-tile, quadrant order
// (0,0),(0,1),(1,0),(1,1); stage tile T+2 into the live slot at phases 1/2/3
// (each region's last ds_read is exactly one phase earlier, sealed by the
// phase-end barrier); counted vmcnt(6) once per K-tile at the group boundary
// (= 3 half-tiles in flight, never drained in steady state).
enum { EP_Q = 0, EP_K = 1, EP_V = 2, EP_WO = 3, EP_FFN1 = 4, EP_FFN2 = 5 };

#define QUAD(MH, NH)                                                                   \
  do {                                                                                 \
    __builtin_amdgcn_s_setprio(1);                                                     \
    acc[MH][NH][0][0] = __builtin_amdgcn_mfma_f32_16x16x32_bf16(a[0][0], b[NH][0][0], acc[MH][NH][0][0], 0, 0, 0); \
    acc[MH][NH][0][0] = __builtin_amdgcn_mfma_f32_16x16x32_bf16(a[0][1], b[NH][0][1], acc[MH][NH][0][0], 0, 0, 0); \
    acc[MH][NH][0][1] = __builtin_amdgcn_mfma_f32_16x16x32_bf16(a[0][0], b[NH][1][0], acc[MH][NH][0][1], 0, 0, 0); \
    acc[MH][NH][0][1] = __builtin_amdgcn_mfma_f32_16x16x32_bf16(a[0][1], b[NH][1][1], acc[MH][NH][0][1], 0, 0, 0); \
    acc[MH][NH][1][0] = __builtin_amdgcn_mfma_f32_16x16x32_bf16(a[1][0], b[NH][0][0], acc[MH][NH][1][0], 0, 0, 0); \
    acc[MH][NH][1][0] = __builtin_amdgcn_mfma_f32_16x16x32_bf16(a[1][1], b[NH][0][1], acc[MH][NH][1][0], 0, 0, 0); \
    acc[MH][NH][1][1] = __builtin_amdgcn_mfma_f32_16x16x32_bf16(a[1][0], b[NH][1][0], acc[MH][NH][1][1], 0, 0, 0); \
    acc[MH][NH][1][1] = __builtin_amdgcn_mfma_f32_16x16x32_bf16(a[1][1], b[NH][1][1], acc[MH][NH][1][1], 0, 0, 0); \
    __builtin_amdgcn_s_setprio(0);                                                     \
  } while (0)

template <int MODE>
__global__ __launch_bounds__(512, 2) void gemm_kernel(
    const unsigned short* __restrict__ A,
    const unsigned short* __restrict__ Bt,
    int K, int N,
    const float* __restrict__ res,
    const float* __restrict__ bias,
    void* __restrict__ out)
{
  __shared__ unsigned short lds[2][3][8192];   // [slot][A,B0,B1][128 rows x 64]

  const int t = threadIdx.x;
  const int w = t >> 6, lane = t & 63;
  const int wm = w >> 2, wn = w & 3;           // 2(M) x 4(N) wave grid
  const int c = lane & 15, g = lane >> 4;
  const int l3 = lane >> 3, l7 = lane & 7;
  const int cs = c & 7;

  const long bm = (long)blockIdx.x * 128;
  const long bn = (long)blockIdx.y * 256;
  const int NT = K >> 6;
  const size_t Ksz = (size_t)K;

  const int scol = (l7 ^ l3) * 8;              // inverse-swizzled source chunk
  const int r0a = w * 16;                      // wave's stage row base

  auto stA = [&](int T) {
    unsigned short* d = &lds[T & 1][0][r0a * 64];
    #pragma unroll
    for (int j = 0; j < 2; j++)
      gload16(A + (bm + r0a + j * 8 + l3) * Ksz + T * 64 + scol, d + j * 512);
  };
  auto stB = [&](int T, int nh) {
    unsigned short* d = &lds[T & 1][1 + nh][r0a * 64];
    #pragma unroll
    for (int j = 0; j < 2; j++)
      gload16(Bt + (bn + nh * 128 + r0a + j * 8 + l3) * Ksz + T * 64 + scol, d + j * 512);
  };

  f32x4 acc[2][2][2][2];                       // [mh][nh][m][n]
  #pragma unroll
  for (int i = 0; i < 2; i++)
    #pragma unroll
    for (int jq = 0; jq < 2; jq++)
      #pragma unroll
      for (int m = 0; m < 2; m++)
        #pragma unroll
        for (int n = 0; n < 2; n++) acc[i][jq][m][n] = (f32x4){0.f, 0.f, 0.f, 0.f};

  // prologue: stage tiles 0 and 1 (6 halves = 12 loads/thread)
  stB(0, 0); stB(0, 1); stA(0);
  stB(1, 0); stB(1, 1); stA(1);
  VMCNT(6);        // tile 0 landed; tile 1's 3 halves may fly
  SBAR();

  const int arow = (wm * 64 + c) * 64;
  const int brow = (wn * 32 + c) * 64;
  const int k0o = (g ^ cs) * 8;                // kk=0 swizzled chunk
  const int k1o = ((4 | g) ^ cs) * 8;          // kk=1

  for (int T = 0; T < NT; T++) {
    const unsigned short* LA  = lds[T & 1][0];
    const unsigned short* LB0 = lds[T & 1][1];
    const unsigned short* LB1 = lds[T & 1][2];
    bf16x8 a[2][2], b[2][2][2];                // a[m][kk]; b[nh][n][kk]

    // ---- phase 0: read A(mh0)+B0; MFMA Q(0,0)
    a[0][0] = *(const bf16x8*)&LA[arow + k0o];
    a[0][1] = *(const bf16x8*)&LA[arow + k1o];
    a[1][0] = *(const bf16x8*)&LA[arow + 1024 + k0o];
    a[1][1] = *(const bf16x8*)&LA[arow + 1024 + k1o];
    b[0][0][0] = *(const bf16x8*)&LB0[brow + k0o];
    b[0][0][1] = *(const bf16x8*)&LB0[brow + k1o];
    b[0][1][0] = *(const bf16x8*)&LB0[brow + 1024 + k0o];
    b[0][1][1] = *(const bf16x8*)&LB0[brow + 1024 + k1o];
    SBAR();
    LGKM0(); SCHEDB();
    QUAD(0, 0);
    SBAR();

    // ---- phase 1: read B1; stage B0(T+2); MFMA Q(0,1)
    b[1][0][0] = *(const bf16x8*)&LB1[brow + k0o];
    b[1][0][1] = *(const bf16x8*)&LB1[brow + k1o];
    b[1][1][0] = *(const bf16x8*)&LB1[brow + 1024 + k0o];
    b[1][1][1] = *(const bf16x8*)&LB1[brow + 1024 + k1o];
    if (T + 2 < NT) stB(T + 2, 0);
    SBAR();
    LGKM0(); SCHEDB();
    QUAD(0, 1);
    SBAR();

    // ---- phase 2: read A(mh1); stage B1(T+2); MFMA Q(1,0)
    a[0][0] = *(const bf16x8*)&LA[arow + 2048 + k0o];
    a[0][1] = *(const bf16x8*)&LA[arow + 2048 + k1o];
    a[1][0] = *(const bf16x8*)&LA[arow + 3072 + k0o];
    a[1][1] = *(const bf16x8*)&LA[arow + 3072 + k1o];
    if (T + 2 < NT) stB(T + 2, 1);
    SBAR();
    LGKM0(); SCHEDB();
    QUAD(1, 0);
    SBAR();

    // ---- phase 3: stage A(T+2); MFMA Q(1,1); boundary vmcnt + barrier
    if (T + 2 < NT) stA(T + 2);
    QUAD(1, 1);
    if (T + 2 < NT) { VMCNT(6); } else { VMCNT(0); }
    SBAR();
  }

  // ---------------- epilogue ----------------
  #pragma unroll
  for (int mh = 0; mh < 2; mh++)
    #pragma unroll
    for (int nh = 0; nh < 2; nh++)
      #pragma unroll
      for (int m = 0; m < 2; m++)
        #pragma unroll
        for (int n = 0; n < 2; n++) {
          const long row0 = bm + wm * 64 + mh * 32 + m * 16 + g * 4;
          const long col  = bn + nh * 128 + wn * 32 + n * 16 + c;
          #pragma unroll
          for (int r = 0; r < 4; r++) {
            const long row = row0 + r;
            float v = acc[mh][nh][m][n][r];
            if constexpr (MODE == EP_Q) {
              ((unsigned short*)out)[(((row >> 11) * NH + (col >> 7)) * (long)SEQ + (row & 2047)) * HD + (col & 127)] =
                  f2bf(v * 0.08838834764831845f);
            } else if constexpr (MODE == EP_K) {
              ((unsigned short*)out)[(((row >> 11) * NH + (col >> 7)) * (long)SEQ + (row & 2047)) * HD + (col & 127)] = f2bf(v);
            } else if constexpr (MODE == EP_V) {
              ((unsigned short*)out)[(((row >> 11) * NH + (col >> 7)) * (long)HD + (col & 127)) * SEQ + (row & 2047)] = f2bf(v);
            } else if constexpr (MODE == EP_WO) {
              ((float*)out)[row * DM + col] = res[row * DM + col] + v;
            } else if constexpr (MODE == EP_FFN1) {
              // tanh-approx GELU (|err| < 3e-3)
              float u = v + bias[col];
              float y = 0.7978845608028654f * (u + 0.044715f * u * u * u);
              float e = __expf(-2.0f * fabsf(y));
              float th = (1.0f - e) / (1.0f + e);
              th = (y < 0.0f) ? -th : th;
              ((unsigned short*)out)[row * (long)N + col] = f2bf(0.5f * u * (1.0f + th));
            } else { // EP_FFN2
              ((float*)out)[row * DM + col] = res[row * DM + col] + v + bias[col];
            }
          }
        }
}

// ---------------- Flash attention, causal + alibi, LDS-staged K/V ----------------
__global__ __launch_bounds__(256) void attn_kernel(
    const unsigned short* __restrict__ Q,
    const unsigned short* __restrict__ Kg,
    const unsigned short* __restrict__ Vt,
    const float* __restrict__ alibi,
    unsigned short* __restrict__ Out)
{
  __shared__ unsigned short lds[2][16384];   // 2 x (16KB K | 16KB V)

  const int bh = blockIdx.x;
  const int h = bh & (NH - 1);
  const int b = bh >> 4;
  const int j = blockIdx.y;                  // pair 0..15
  const int t = threadIdx.x;
  const int w = t >> 6;                      // wave 0..3
  const int lane = t & 63;
  const int c = lane & 15, g = lane >> 4;
  const int cx = (c & 7) << 4;               // read-side XOR swizzle

  const char* KpB = (const char*)(Kg + (size_t)bh * SEQ * HD);
  const char* VpB = (const char*)(Vt + (size_t)bh * SEQ * HD);
  const unsigned short* Qp = Q + (size_t)bh * SEQ * HD;
  const float* Ah = alibi + (size_t)h * SEQ * SEQ;

  #pragma unroll 1
  for (int half = 0; half < 2; half++) {
    const int cidx = half ? (31 - j) : j;
    const int nt = cidx + 1;                 // kv tiles for this chunk
    const int qb = cidx * 64;
    const int q0 = qb + w * 16, qc = q0 + c;

    bf16x8 qf[4];
    #pragma unroll
    for (int dt = 0; dt < 4; dt++)
      qf[dt] = *(const bf16x8*)(Qp + (size_t)qc * HD + dt * 32 + g * 8);

    f32x4 oacc[8];
    #pragma unroll
    for (int d = 0; d < 8; d++) oacc[d] = (f32x4){0.f, 0.f, 0.f, 0.f};
    float m_run = -1e30f, s_run = 0.f;
    const float* Ap = Ah + (size_t)qc * SEQ;

    auto stage = [&](int tt, unsigned short* dst) {
      const size_t kvo = (size_t)tt * 64;
      #pragma unroll
      for (int k = 0; k < 8; k++) {
        const int o = w * 8192 + k * 1024 + lane * 16;
        if (w < 2) {
          const int so = o ^ (((o >> 8) & 7) << 4);        // inverse swizzle (involution)
          gload16(KpB + kvo * 256 + so, dst + ((w * 8192 + k * 1024) >> 1));
        } else {
          const int o2 = o - 16384;
          const int d = o2 >> 7, win = o2 & 127;
          gload16(VpB + (size_t)d * 4096 + kvo * 2 + (win ^ ((d & 7) << 4)),
                  dst + ((w * 8192 + k * 1024) >> 1));
        }
      }
    };

    stage(0, lds[0]);
    __syncthreads();
    int buf = 0;

    for (int tt = 0; tt < nt; tt++) {
      if (tt + 1 < nt) stage(tt + 1, lds[buf ^ 1]);
      const unsigned short* LK = lds[buf];
      const unsigned short* LV = lds[buf] + 8192;
      const int kv0 = tt * 64;

      f32x4 sc[4];
      #pragma unroll
      for (int st = 0; st < 4; st++) sc[st] = (f32x4){0.f, 0.f, 0.f, 0.f};
      #pragma unroll
      for (int dt = 0; dt < 4; dt++)
        #pragma unroll
        for (int st = 0; st < 4; st++) {
          bf16x8 kf = *(const bf16x8*)&LK[(st * 4096 + c * 256 + ((dt * 64 + g * 16) ^ cx)) >> 1];
          sc[st] = __builtin_amdgcn_mfma_f32_16x16x32_bf16(kf, qf[dt], sc[st], 0, 0, 0);
        }

      float4 al[4];
      #pragma unroll
      for (int st = 0; st < 4; st++) al[st] = *(const float4*)(Ap + kv0 + st * 16 + g * 4);
      float scr[16];
      #pragma unroll
      for (int st = 0; st < 4; st++) {
        scr[st*4+0] = (kv0 + st*16 + g*4 + 0 > qc) ? -1e30f : sc[st][0] + al[st].x;
        scr[st*4+1] = (kv0 + st*16 + g*4 + 1 > qc) ? -1e30f : sc[st][1] + al[st].y;
        scr[st*4+2] = (kv0 + st*16 + g*4 + 2 > qc) ? -1e30f : sc[st][2] + al[st].z;
        scr[st*4+3] = (kv0 + st*16 + g*4 + 3 > qc) ? -1e30f : sc[st][3] + al[st].w;
      }

      float tm = scr[0];
      #pragma unroll
      for (int i = 1; i < 16; i++) tm = fmaxf(tm, scr[i]);
      tm = fmaxf(tm, __shfl_xor(tm, 16));
      tm = fmaxf(tm, __shfl_xor(tm, 32));
      const float m_new = fmaxf(m_run, tm);
      const float corr = __expf(m_run - m_new);
      float pv[16]; float ps = 0.f;
      #pragma unroll
      for (int i = 0; i < 16; i++) { pv[i] = __expf(scr[i] - m_new); ps += pv[i]; }
      ps += __shfl_xor(ps, 16);
      ps += __shfl_xor(ps, 32);
      s_run = s_run * corr + ps;
      m_run = m_new;

      short4_t pf[4];
      #pragma unroll
      for (int st = 0; st < 4; st++) {
        pf[st][0] = (short)f2bf(pv[st*4+0]); pf[st][1] = (short)f2bf(pv[st*4+1]);
        pf[st][2] = (short)f2bf(pv[st*4+2]); pf[st][3] = (short)f2bf(pv[st*4+3]);
      }

      float cf[4];
      #pragma unroll
      for (int r = 0; r < 4; r++) cf[r] = __shfl(corr, g * 4 + r);

      #pragma unroll
      for (int dt = 0; dt < 8; dt++) {
        f32x4 o = oacc[dt];
        o[0] *= cf[0]; o[1] *= cf[1]; o[2] *= cf[2]; o[3] *= cf[3];
        #pragma unroll
        for (int st = 0; st < 4; st++) {
          short4_t vf = *(const short4_t*)&LV[((dt * 16 + c) * 128 + ((st * 32 + g * 8) ^ cx)) >> 1];
          o = __builtin_amdgcn_mfma_f32_16x16x16bf16_1k(pf[st], vf, o, 0, 0, 0);
        }
        oacc[dt] = o;
      }

      __syncthreads();
      buf ^= 1;
    }

    float inv[4];
    #pragma unroll
    for (int r = 0; r < 4; r++) inv[r] = 1.0f / __shfl(s_run, g * 4 + r);
    #pragma unroll
    for (int dt = 0; dt < 8; dt++)
      #pragma unroll
      for (int r = 0; r < 4; r++)
        Out[(size_t)(b * SEQ + q0 + g * 4 + r) * DM + h * HD + dt * 16 + c] =
            f2bf(oacc[dt][r] * inv[r]);
  }
}

// ---------------- launch ----------------
extern "C" void kernel_launch(void* const* d_in, const int* in_sizes, int n_in,
                              void* d_out, int out_size, void* d_ws, size_t ws_size,
                              hipStream_t stream) {
  const float* x     = (const float*)d_in[0];
  const float* alibi = (const float*)d_in[1];
  const float* Wq    = (const float*)d_in[2];
  const float* Wk    = (const float*)d_in[3];
  const float* Wv    = (const float*)d_in[4];
  const float* Wo    = (const float*)d_in[5];
  const float* ln1g  = (const float*)d_in[6];
  const float* ln1b  = (const float*)d_in[7];
  const float* ln2g  = (const float*)d_in[8];
  const float* ln2b  = (const float*)d_in[9];
  const float* w1    = (const float*)d_in[10];
  const float* b1    = (const float*)d_in[11];
  const float* w2    = (const float*)d_in[12];
  const float* b2    = (const float*)d_in[13];

  char* ws = (char*)d_ws;
  float*          hbuf = (float*)(ws);                                // 32MB f32 h
  unsigned short* xn   = (unsigned short*)(ws + (32ull  << 20));      // 16MB bf16 (xn, later n2)
  unsigned short* qb   = (unsigned short*)(ws + (48ull  << 20));      // 16MB
  unsigned short* kb   = (unsigned short*)(ws + (64ull  << 20));      // 16MB
  unsigned short* vt   = (unsigned short*)(ws + (80ull  << 20));      // 16MB
  unsigned short* ao   = (unsigned short*)(ws + (96ull  << 20));      // 16MB attn_out
  unsigned short* wt   = (unsigned short*)(ws + (112ull << 20));      // 32MB weight scratch
  unsigned short* a1   = (unsigned short*)(ws + (48ull  << 20));      // 64MB (reuses q/k/vt/ao)

  dim3 blk256(256);
  dim3 blk512(512);
  dim3 tb(32, 8);

  ln_kernel<<<MROWS, blk256, 0, stream>>>(x, ln1g, ln1b, xn);

  transpose_kernel<<<dim3(DM/32, DM/32), tb, 0, stream>>>(Wq, wt, DM, DM);
  gemm_kernel<EP_Q><<<dim3(MROWS/128, DM/256), blk512, 0, stream>>>(xn, wt, DM, DM, nullptr, nullptr, qb);
  transpose_kernel<<<dim3(DM/32, DM/32), tb, 0, stream>>>(Wk, wt, DM, DM);
  gemm_kernel<EP_K><<<dim3(MROWS/128, DM/256), blk512, 0, stream>>>(xn, wt, DM, DM, nullptr, nullptr, kb);
  transpose_kernel<<<dim3(DM/32, DM/32), tb, 0, stream>>>(Wv, wt, DM, DM);
  gemm_kernel<EP_V><<<dim3(MROWS/128, DM/256), blk512, 0, stream>>>(xn, wt, DM, DM, nullptr, nullptr, vt);

  attn_kernel<<<dim3(NH * 2, 16), blk256, 0, stream>>>(qb, kb, vt, alibi, ao);

  transpose_kernel<<<dim3(DM/32, DM/32), tb, 0, stream>>>(Wo, wt, DM, DM);
  gemm_kernel<EP_WO><<<dim3(MROWS/128, DM/256), blk512, 0, stream>>>(ao, wt, DM, DM, x, nullptr, hbuf);

  ln_kernel<<<MROWS, blk256, 0, stream>>>(hbuf, ln2g, ln2b, xn);

  transpose_kernel<<<dim3(DFF/32, DM/32), tb, 0, stream>>>(w1, wt, DM, DFF);
  gemm_kernel<EP_FFN1><<<dim3(MROWS/128, DFF/256), blk512, 0, stream>>>(xn, wt, DM, DFF, nullptr, b1, a1);

  transpose_kernel<<<dim3(DM/32, DFF/32), tb, 0, stream>>>(w2, wt, DFF, DM);
  gemm_kernel<EP_FFN2><<<dim3(MROWS/128, DM/256), blk512, 0, stream>>>(a1, wt, DFF, DM, hbuf, b2, (float*)d_out);
}